// Round 6
// baseline (113363.794 us; speedup 1.0000x reference)
//
#include <hip/hip_runtime.h>

// HyperLSTM + MDN decoder — f32 in, f32 out.
// R12: persistent kernel, GRID=256 x TPB=512 (R9-proven coop config; R11's
// 512-block ask exceeded coop validation -> silent no-launch). Custom
// monotonic-counter grid barrier (~2-3us vs cg::sync ~35us). 3 barriers/step:
// A (tile GEMMs, global-broadcast-A — zero LDS transpose conflicts) ->
// B (gate-sum + hh/ch + z GEMV | proj epilogue + MDN) -> C (einsum + LSTM).
// Fallback to plain launch if coop errors (grid == CU count => co-resident).
#define MM     20
#define LATENT 128
#define IN_DIM 133
#define HD     1024
#define HD4    4096
#define HY     256
#define FF     64
#define NSEQ   128
#define BB     64
#define OUT_DIM 123   // 6*M+3
#define GRID   256
#define TPB    512

// Persistent state + per-step intermediates (A-operands transposed: [k][b]).
__device__ float g_hT  [HD * BB];
__device__ float g_c   [BB * HD];
__device__ float g_ch  [BB * HY];
__device__ float g_hhT [HY * BB];
__device__ float g_xT  [NSEQ * 192 * BB];   // strokes^T, k-padded to 192
__device__ float g_hWh [8][BB * HD4];       // h@Wh split-K partials (k=128)
__device__ float g_xWx [BB * HD4];
__device__ float g_gH  [8][BB * HD];        // h-part of hyper gates
__device__ float g_ghh [2][BB * HD];        // hh@Whh_hy
__device__ float g_gx  [BB * HD];           // x-part of hyper gates
__device__ float g_z   [BB * 3 * HY];
__device__ float g_proj[8][BB * 128];       // proj split-K partials
__device__ unsigned g_barCnt;

__device__ __forceinline__ float sigf(float x) { return 1.0f / (1.0f + expf(-x)); }

__device__ __forceinline__ void gload_lds16(const float* g, float* l) {
    __builtin_amdgcn_global_load_lds(
        (const __attribute__((address_space(1))) void*)g,
        (__attribute__((address_space(3))) void*)l, 16, 0, 0);
}

// grid barrier: monotonic counter, 1 atomicAdd + agent-scope spin (thread 0).
__device__ __forceinline__ void gridbar(unsigned& tgt) {
    tgt += GRID;
    __syncthreads();                 // all block mem ops drained (vmcnt 0)
    if (threadIdx.x == 0) {
        __threadfence();             // release across XCD L2s
        __hip_atomic_fetch_add(&g_barCnt, 1u, __ATOMIC_RELEASE,
                               __HIP_MEMORY_SCOPE_AGENT);
        while (__hip_atomic_load(&g_barCnt, __ATOMIC_ACQUIRE,
                                 __HIP_MEMORY_SCOPE_AGENT) < tgt)
            __builtin_amdgcn_s_sleep(2);
        __threadfence();             // acquire
    }
    __syncthreads();
}

struct Params {
    const float *z, *strokes, *fc_in_w, *fc_in_b, *fc_proj_w, *fc_proj_b;
    const float *Wx, *Wh, *b0w, *Wxh_hy, *Whh_hy, *b_hy;
    const float *Wzx, *bzx, *Wzh, *bzh, *Wzb, *Dx, *Dh, *Db;
    float* out;
};

// 64b x 256c tile, np k-panels of 64. 512 thr: 8b x 4c each. Wt = 64KB.
__device__ __forceinline__ void gemm256(
    const float* AT, const float* Wp, int ldw, int wrows, int co, int np,
    float* Op, int ldo, float* Wt, int tid)
{
    int cq = tid & 63, bq = tid >> 6;
    float4 acc0 = {0,0,0,0}, acc1 = {0,0,0,0}, acc2 = {0,0,0,0}, acc3 = {0,0,0,0};
    float4 acc4 = {0,0,0,0}, acc5 = {0,0,0,0}, acc6 = {0,0,0,0}, acc7 = {0,0,0,0};
    for (int pn = 0; pn < np; pn++) {
        #pragma unroll
        for (int q = 0; q < 8; q++) {
            int s = (q << 9) + tid;            // float4 slot 0..4095
            int r = s >> 6, c4 = s & 63;
            int kr = (pn << 6) + r; if (kr >= wrows) kr = wrows - 1;
            gload_lds16(Wp + kr * ldw + co + (c4 << 2), Wt + (s << 2));
        }
        __syncthreads();                       // staging landed (vmcnt drain)
        const float* Ap2 = AT + (pn << 12) + (bq << 3);
        const float* Wcc = Wt + (cq << 2);
        #pragma unroll 8
        for (int k = 0; k < 64; k++) {
            float4 a0 = *(const float4*)(Ap2 + (k << 6));
            float4 a1 = *(const float4*)(Ap2 + (k << 6) + 4);
            float4 w  = *(const float4*)(Wcc + (k << 8));
            acc0.x += a0.x*w.x; acc0.y += a0.x*w.y; acc0.z += a0.x*w.z; acc0.w += a0.x*w.w;
            acc1.x += a0.y*w.x; acc1.y += a0.y*w.y; acc1.z += a0.y*w.z; acc1.w += a0.y*w.w;
            acc2.x += a0.z*w.x; acc2.y += a0.z*w.y; acc2.z += a0.z*w.z; acc2.w += a0.z*w.w;
            acc3.x += a0.w*w.x; acc3.y += a0.w*w.y; acc3.z += a0.w*w.z; acc3.w += a0.w*w.w;
            acc4.x += a1.x*w.x; acc4.y += a1.x*w.y; acc4.z += a1.x*w.z; acc4.w += a1.x*w.w;
            acc5.x += a1.y*w.x; acc5.y += a1.y*w.y; acc5.z += a1.y*w.z; acc5.w += a1.y*w.w;
            acc6.x += a1.z*w.x; acc6.y += a1.z*w.y; acc6.z += a1.z*w.z; acc6.w += a1.z*w.w;
            acc7.x += a1.w*w.x; acc7.y += a1.w*w.y; acc7.z += a1.w*w.z; acc7.w += a1.w*w.w;
        }
        __syncthreads();                       // done reading before next stage
    }
    float* op = Op + (bq << 3) * ldo + co + (cq << 2);
    *(float4*)(op)           = acc0;  *(float4*)(op + ldo)     = acc1;
    *(float4*)(op + 2 * ldo) = acc2;  *(float4*)(op + 3 * ldo) = acc3;
    *(float4*)(op + 4 * ldo) = acc4;  *(float4*)(op + 5 * ldo) = acc5;
    *(float4*)(op + 6 * ldo) = acc6;  *(float4*)(op + 7 * ldo) = acc7;
}

// 64b x 128c tile, np k-panels of 64. 512 thr: 4b x 4c each. Wt = 32KB.
// wS: scalar-staged with column pad (proj, ldw==OUT_DIM).
__device__ __forceinline__ void gemm128(
    const float* AT, const float* Wp, int ldw, int wrows, int co, int np,
    bool wS, float* Op, int ldo, float* Wt, int tid)
{
    int cq = tid & 31, bq = tid >> 5;
    float4 acc0 = {0,0,0,0}, acc1 = {0,0,0,0}, acc2 = {0,0,0,0}, acc3 = {0,0,0,0};
    for (int pn = 0; pn < np; pn++) {
        if (!wS) {
            #pragma unroll
            for (int q = 0; q < 4; q++) {
                int s = (q << 9) + tid;        // float4 slot 0..2047
                int r = s >> 5, c4 = s & 31;
                int kr = (pn << 6) + r; if (kr >= wrows) kr = wrows - 1;
                gload_lds16(Wp + kr * ldw + co + (c4 << 2), Wt + (s << 2));
            }
        } else {
            #pragma unroll
            for (int q = 0; q < 16; q++) {
                int idx = (q << 9) + tid;      // 0..8191
                int r = idx >> 7, c = idx & 127;
                int kr = (pn << 6) + r; if (kr >= wrows) kr = wrows - 1;
                Wt[idx] = (c < OUT_DIM) ? Wp[kr * ldw + c] : 0.f;
            }
        }
        __syncthreads();
        const float* Ap2 = AT + (pn << 12) + (bq << 2);
        const float* Wcc = Wt + (cq << 2);
        #pragma unroll 8
        for (int k = 0; k < 64; k++) {
            float4 a = *(const float4*)(Ap2 + (k << 6));
            float4 w = *(const float4*)(Wcc + (k << 7));
            acc0.x += a.x*w.x; acc0.y += a.x*w.y; acc0.z += a.x*w.z; acc0.w += a.x*w.w;
            acc1.x += a.y*w.x; acc1.y += a.y*w.y; acc1.z += a.y*w.z; acc1.w += a.y*w.w;
            acc2.x += a.z*w.x; acc2.y += a.z*w.y; acc2.z += a.z*w.z; acc2.w += a.z*w.w;
            acc3.x += a.w*w.x; acc3.y += a.w*w.y; acc3.z += a.w*w.z; acc3.w += a.w*w.w;
        }
        __syncthreads();
    }
    float* op = Op + (bq << 2) * ldo + co + (cq << 2);
    *(float4*)(op)           = acc0;  *(float4*)(op + ldo)     = acc1;
    *(float4*)(op + 2 * ldo) = acc2;  *(float4*)(op + 3 * ldo) = acc3;
}

__global__ void reset_kernel() { g_barCnt = 0; }

__global__ __launch_bounds__(TPB, 2) void fused(Params p)
{
    __shared__ float pool[16384];       // 64 KB: Wt | gsum+hhB | zC+preC
    int blk = blockIdx.x, tid = threadIdx.x;
    unsigned barTgt = 0;

    // ---- INIT: s0 GEMM (blocks 0-63) + strokes transpose (blocks 64-191) ----
    if (blk < 64) {
        int b = blk;
        if (tid < LATENT) pool[tid] = p.z[b * LATENT + tid];
        __syncthreads();
        for (int j = tid; j < 2560; j += TPB) {
            float acc = p.fc_in_b[j];
            #pragma unroll 4
            for (int k = 0; k < LATENT; k++) acc += pool[k] * p.fc_in_w[k * 2560 + j];
            float s = tanhf(acc);
            if      (j < 1024) g_hT [j * 64 + b]            = s;
            else if (j < 2048) g_c  [b * 1024 + (j - 1024)] = s;
            else if (j < 2304) g_hhT[(j - 2048) * 64 + b]   = s;
            else               g_ch [b * 256 + (j - 2304)]  = s;
        }
    } else if (blk < 192) {
        int t0 = blk - 64;
        for (int i = tid; i < 192 * 64; i += TPB) {
            int k = i >> 6, b = i & 63;
            g_xT[t0 * 192 * 64 + i] =
                (k < IN_DIM) ? p.strokes[(t0 * BB + b) * IN_DIM + k] : 0.f;
        }
    }
    gridbar(barTgt);

    for (int t = 0; t <= NSEQ; t++) {
        // ================= phase A: tile GEMMs =================
        {
            int u = blk;
            if (u < 128) {                              // h @ Wh (256-col)
                if (t < NSEQ) {
                    int ch = u >> 4, ct = u & 15;
                    gemm256(g_hT + ch * 128 * 64, p.Wh + ch * 128 * HD4,
                            HD4, 128, ct * 256, 2, g_hWh[ch], HD4, pool, tid);
                }
            } else if (u < 160) {                       // h-part hyper gates
                if (t < NSEQ) {
                    int i = u - 128, ch = i >> 2, ct = i & 3;
                    gemm256(g_hT + ch * 128 * 64,
                            p.Wxh_hy + (133 + ch * 128) * HD,
                            HD, 128, ct * 256, 2, g_gH[ch], HD, pool, tid);
                }
            } else if (u < 168) {                       // hh @ Whh_hy
                if (t < NSEQ) {
                    int i = u - 160, ch = i >> 2, ct = i & 3;
                    gemm256(g_hhT + ch * 128 * 64, p.Whh_hy + ch * 128 * HD,
                            HD, 128, ct * 256, 2, g_ghh[ch], HD, pool, tid);
                }
            } else if (u < 200) {                       // x @ Wx (128-col)
                if (t < NSEQ) {
                    int ct = u - 168;
                    gemm128(g_xT + t * 192 * 64, p.Wx,
                            HD4, IN_DIM, ct * 128, 3, false, g_xWx, HD4, pool, tid);
                }
            } else if (u < 208) {                       // x-part hyper gates
                if (t < NSEQ) {
                    int ct = u - 200;
                    gemm128(g_xT + t * 192 * 64, p.Wxh_hy,
                            HD, IN_DIM, ct * 128, 3, false, g_gx, HD, pool, tid);
                }
            } else if (u < 216) {                       // proj of h_{t-1}
                if (t > 0) {
                    int ch = u - 208;
                    gemm128(g_hT + ch * 128 * 64, p.fc_proj_w + ch * 128 * OUT_DIM,
                            OUT_DIM, 128, 0, 2, true, g_proj[ch], 128, pool, tid);
                }
            }
        }
        gridbar(barTgt);

        // ========== phase B: gate-sum + hh/ch + z | proj epilogue + MDN ======
        if (blk < 64) {
            if (t < NSEQ) {
                int b = blk, base = b * HD;
                float* gsum = pool; float* hhB = pool + 1024;
                #pragma unroll
                for (int half = 0; half < 2; half++) {
                    int j = (half << 9) + tid;
                    float a = p.b_hy[j];
                    #pragma unroll
                    for (int c = 0; c < 8; c++) a += g_gH[c][base + j];
                    a += g_ghh[0][base + j] + g_ghh[1][base + j] + g_gx[base + j];
                    gsum[j] = a;
                }
                __syncthreads();
                if (tid < 256) {
                    float gi = gsum[tid],       gf = gsum[256 + tid];
                    float gg = gsum[512 + tid], go = gsum[768 + tid];
                    float ch = g_ch[b * HY + tid];
                    ch = sigf(gf) * ch + sigf(gi) * tanhf(gg);
                    float hh = sigf(go) * tanhf(ch);
                    g_ch[b * HY + tid] = ch;
                    g_hhT[tid * 64 + b] = hh;
                    hhB[tid] = hh;
                }
                __syncthreads();
                for (int o = tid; o < 768; o += TPB) {
                    int ten = o >> 8, oo = o & 255;
                    const float* Wz = (ten == 0) ? p.Wzx : (ten == 1) ? p.Wzh : p.Wzb;
                    float acc = (ten == 0) ? p.bzx[oo] : (ten == 1) ? p.bzh[oo] : 0.f;
                    #pragma unroll 8
                    for (int k = 0; k < HY; k++) acc += hhB[k] * Wz[(k << 8) + oo];
                    g_z[b * 768 + o] = acc;
                }
            }
        } else if (blk < 128) {
            if (t > 0) {                        // proj epilogue + MDN, tp = t-1
                int b = blk - 64, tp = t - 1, base7 = b << 7;
                int c = tid;
                if (c < 120) {
                    float v = p.fc_proj_b[c];
                    #pragma unroll
                    for (int q = 0; q < 8; q++) v += g_proj[q][base7 + c];
                    int m = c / 6, r = c - m * 6;
                    int oidx = tp * (MM * BB) + m * BB + b;
                    if      (r == 0) p.out[oidx]          = 1.0f;  // size-1 softmax
                    else if (r == 1) p.out[163840 + oidx] = v;
                    else if (r == 2) p.out[327680 + oidx] = v;
                    else if (r == 3) p.out[491520 + oidx] = expf(v);
                    else if (r == 4) p.out[655360 + oidx] = expf(v);
                    else             p.out[819200 + oidx] = tanhf(v);
                } else if (c == 120) {                     // pen-state softmax
                    float p0 = p.fc_proj_b[120], p1 = p.fc_proj_b[121],
                          p2 = p.fc_proj_b[122];
                    #pragma unroll
                    for (int q = 0; q < 8; q++) {
                        p0 += g_proj[q][base7 + 120];
                        p1 += g_proj[q][base7 + 121];
                        p2 += g_proj[q][base7 + 122];
                    }
                    float mx = fmaxf(p0, fmaxf(p1, p2));
                    float e0 = expf(p0 - mx), e1 = expf(p1 - mx), e2 = expf(p2 - mx);
                    float s = e0 + e1 + e2;
                    int ob = 983040 + tp * (BB * 3) + b * 3;
                    p.out[ob + 0] = e0 / s; p.out[ob + 1] = e1 / s;
                    p.out[ob + 2] = e2 / s;
                }
            }
        }
        if (t == NSEQ) break;                   // uniform exit (no C needed)
        gridbar(barTgt);

        // ============ phase C: einsum + combine + main LSTM update ===========
        {
            int bg = blk >> 5, sl = blk & 31;
            int hi0 = sl << 5;
            float* zC = pool;                   // 6144 floats
            float* preC = pool + 6144;          // 1024 floats
            {
                const float4* src = (const float4*)(g_z + bg * 8 * 768);
                float4* dst = (float4*)zC;
                for (int i = tid; i < 1536; i += TPB) dst[i] = src[i];
            }
            __syncthreads();
            int hi_l = tid & 31, gq = (tid >> 5) & 3, b4 = tid >> 7;
            int hi = hi0 + hi_l;
            const float* dxp = p.Dx + gq * 64 * HD + hi;
            const float* dhp = p.Dh + gq * 64 * HD + hi;
            const float* dbp = p.Db + gq * 64 * HD + hi;
            const float* z0 = zC + b4 * 768;
            const float* z1 = zC + (b4 + 4) * 768;
            int zo = gq << 6;
            float ax0 = 0.f, ah0 = 0.f, ab0 = 0.f, ax1 = 0.f, ah1 = 0.f, ab1 = 0.f;
            #pragma unroll 4
            for (int f = 0; f < FF; f++) {
                float dx = dxp[f * HD], dh = dhp[f * HD], db = dbp[f * HD];
                ax0 += z0[zo + f] * dx; ah0 += z0[256 + zo + f] * dh;
                ab0 += z0[512 + zo + f] * db;
                ax1 += z1[zo + f] * dx; ah1 += z1[256 + zo + f] * dh;
                ab1 += z1[512 + zo + f] * db;
            }
            int idx = (gq << 10) + hi;
            int b0i = (bg << 3) + b4, b1i = b0i + 4;
            float hw0 = 0.f, hw1 = 0.f;
            #pragma unroll
            for (int q = 0; q < 8; q++) {
                hw0 += g_hWh[q][b0i * HD4 + idx];
                hw1 += g_hWh[q][b1i * HD4 + idx];
            }
            float xw0 = g_xWx[b0i * HD4 + idx], xw1 = g_xWx[b1i * HD4 + idx];
            float bw = p.b0w[idx];
            float pre0 = ax0 * xw0 + ah0 * hw0 + ab0 + bw;
            float pre1 = ax1 * xw1 + ah1 * hw1 + ab1 + bw;
            preC[((b4 << 2) + gq) * 32 + hi_l]       = pre0;
            preC[(((b4 + 4) << 2) + gq) * 32 + hi_l] = pre1;
            __syncthreads();
            if (tid < 256) {
                int bi = tid >> 5, hl = tid & 31;
                int b = (bg << 3) + bi, ha = b * HD + hi0 + hl;
                float pi = preC[((bi << 2) + 0) * 32 + hl];
                float pf = preC[((bi << 2) + 1) * 32 + hl];
                float pg = preC[((bi << 2) + 2) * 32 + hl];
                float po = preC[((bi << 2) + 3) * 32 + hl];
                float cv = g_c[ha];
                float nc = sigf(pf) * cv + sigf(pi) * tanhf(pg);
                float nh = sigf(po) * tanhf(nc);
                g_c[ha] = nc;
                g_hT[(hi0 + hl) * 64 + b] = nh;
            }
        }
        gridbar(barTgt);
    }
}

// ---------------------------------------------------------------------------
extern "C" void kernel_launch(void* const* d_in, const int* in_sizes, int n_in,
                              void* d_out, int out_size, void* d_ws, size_t ws_size,
                              hipStream_t stream)
{
    Params p;
    p.z         = (const float*)d_in[0];
    p.strokes   = (const float*)d_in[1];
    p.fc_in_w   = (const float*)d_in[2];
    p.fc_in_b   = (const float*)d_in[3];
    p.fc_proj_w = (const float*)d_in[4];
    p.fc_proj_b = (const float*)d_in[5];
    p.Wx        = (const float*)d_in[6];
    p.Wh        = (const float*)d_in[7];
    p.b0w       = (const float*)d_in[8];
    p.Wxh_hy    = (const float*)d_in[9];
    p.Whh_hy    = (const float*)d_in[10];
    p.b_hy      = (const float*)d_in[11];
    p.Wzx       = (const float*)d_in[12];
    p.bzx       = (const float*)d_in[13];
    p.Wzh       = (const float*)d_in[14];
    p.bzh       = (const float*)d_in[15];
    p.Wzb       = (const float*)d_in[16];
    p.Dx        = (const float*)d_in[17];
    p.Dh        = (const float*)d_in[18];
    p.Db        = (const float*)d_in[19];
    p.out       = (float*)d_out;
    (void)d_ws; (void)ws_size; (void)in_sizes; (void)n_in; (void)out_size;

    reset_kernel<<<1, 1, 0, stream>>>();
    void* args[] = { (void*)&p };
    hipError_t e = hipLaunchCooperativeKernel((const void*)fused, dim3(GRID),
                                              dim3(TPB), args, 0, stream);
    if (e != hipSuccess) {
        // grid == CU count, 1 block/CU guaranteed resident -> barrier safe
        fused<<<dim3(GRID), dim3(TPB), 0, stream>>>(p);
    }
}

// Round 7
// 7783.855 us; speedup vs baseline: 14.5640x; 14.5640x over previous
//
#include <hip/hip_runtime.h>

// HyperLSTM + MDN decoder — f32 in, f32 out.
// R13: R12's verified phase code as 3 PLAIN KERNELS per step (no persistent
// barriers — R9/R12 proved grid-sync costs 35-100us vs ~5us kernel boundary).
// vs R10: k=128 units (stage amortized 2x, 8 partials not 16), 256-col tiles,
// K2 gate-sum reads 11 arrays (was 23), K3 sums 8 partials (was 16).
#define MM     20
#define LATENT 128
#define IN_DIM 133
#define HD     1024
#define HD4    4096
#define HY     256
#define FF     64
#define NSEQ   128
#define BB     64
#define OUT_DIM 123   // 6*M+3

// Persistent state + per-step intermediates (A-operands transposed: [k][b]).
__device__ float g_hT  [HD * BB];
__device__ float g_c   [BB * HD];
__device__ float g_ch  [BB * HY];
__device__ float g_hhT [HY * BB];
__device__ float g_xT  [NSEQ * 192 * BB];   // strokes^T, k-padded to 192
__device__ float g_hWh [8][BB * HD4];       // h@Wh split-K partials (k=128)
__device__ float g_xWx [BB * HD4];
__device__ float g_gH  [8][BB * HD];        // h-part of hyper gates
__device__ float g_ghh [2][BB * HD];        // hh@Whh_hy
__device__ float g_gx  [BB * HD];           // x-part of hyper gates
__device__ float g_z   [BB * 3 * HY];
__device__ float g_proj[8][BB * 128];       // proj split-K partials

__device__ __forceinline__ float sigf(float x) { return 1.0f / (1.0f + expf(-x)); }

__device__ __forceinline__ void gload_lds16(const float* g, float* l) {
    __builtin_amdgcn_global_load_lds(
        (const __attribute__((address_space(1))) void*)g,
        (__attribute__((address_space(3))) void*)l, 16, 0, 0);
}

// ---------------------------------------------------------------------------
// init: s0 = tanh(z @ fc_in_w + fc_in_b).  grid 64 x 256
// ---------------------------------------------------------------------------
__global__ __launch_bounds__(256) void init_kernel(
    const float* __restrict__ z, const float* __restrict__ fc_in_w,
    const float* __restrict__ fc_in_b)
{
    int b = blockIdx.x, tid = threadIdx.x;
    __shared__ float zs[LATENT];
    if (tid < LATENT) zs[tid] = z[b * LATENT + tid];
    __syncthreads();
    for (int j = tid; j < 2560; j += 256) {
        float acc = fc_in_b[j];
        #pragma unroll 4
        for (int k = 0; k < LATENT; k++) acc += zs[k] * fc_in_w[k * 2560 + j];
        float s = tanhf(acc);
        if      (j < 1024) g_hT [j * 64 + b]            = s;
        else if (j < 2048) g_c  [b * 1024 + (j - 1024)] = s;
        else if (j < 2304) g_hhT[(j - 2048) * 64 + b]   = s;
        else               g_ch [b * 256 + (j - 2304)]  = s;
    }
}

__global__ __launch_bounds__(256) void xt_kernel(const float* __restrict__ strokes)
{
    int t = blockIdx.x, tid = threadIdx.x;
    for (int i = tid; i < 192 * 64; i += 256) {
        int k = i >> 6, b = i & 63;
        g_xT[t * 192 * 64 + i] =
            (k < IN_DIM) ? strokes[(t * BB + b) * IN_DIM + k] : 0.f;
    }
}

// 64b x 256c tile, np k-panels of 64. 512 thr: 8b x 4c each. Wt = 64KB.
__device__ __forceinline__ void gemm256(
    const float* AT, const float* Wp, int ldw, int wrows, int co, int np,
    float* Op, int ldo, float* Wt, int tid)
{
    int cq = tid & 63, bq = tid >> 6;
    float4 acc0 = {0,0,0,0}, acc1 = {0,0,0,0}, acc2 = {0,0,0,0}, acc3 = {0,0,0,0};
    float4 acc4 = {0,0,0,0}, acc5 = {0,0,0,0}, acc6 = {0,0,0,0}, acc7 = {0,0,0,0};
    for (int pn = 0; pn < np; pn++) {
        #pragma unroll
        for (int q = 0; q < 8; q++) {
            int s = (q << 9) + tid;            // float4 slot 0..4095
            int r = s >> 6, c4 = s & 63;
            int kr = (pn << 6) + r; if (kr >= wrows) kr = wrows - 1;
            gload_lds16(Wp + kr * ldw + co + (c4 << 2), Wt + (s << 2));
        }
        __syncthreads();                       // staging landed (vmcnt drain)
        const float* Ap2 = AT + (pn << 12) + (bq << 3);
        const float* Wcc = Wt + (cq << 2);
        #pragma unroll 8
        for (int k = 0; k < 64; k++) {
            float4 a0 = *(const float4*)(Ap2 + (k << 6));
            float4 a1 = *(const float4*)(Ap2 + (k << 6) + 4);
            float4 w  = *(const float4*)(Wcc + (k << 8));
            acc0.x += a0.x*w.x; acc0.y += a0.x*w.y; acc0.z += a0.x*w.z; acc0.w += a0.x*w.w;
            acc1.x += a0.y*w.x; acc1.y += a0.y*w.y; acc1.z += a0.y*w.z; acc1.w += a0.y*w.w;
            acc2.x += a0.z*w.x; acc2.y += a0.z*w.y; acc2.z += a0.z*w.z; acc2.w += a0.z*w.w;
            acc3.x += a0.w*w.x; acc3.y += a0.w*w.y; acc3.z += a0.w*w.z; acc3.w += a0.w*w.w;
            acc4.x += a1.x*w.x; acc4.y += a1.x*w.y; acc4.z += a1.x*w.z; acc4.w += a1.x*w.w;
            acc5.x += a1.y*w.x; acc5.y += a1.y*w.y; acc5.z += a1.y*w.z; acc5.w += a1.y*w.w;
            acc6.x += a1.z*w.x; acc6.y += a1.z*w.y; acc6.z += a1.z*w.z; acc6.w += a1.z*w.w;
            acc7.x += a1.w*w.x; acc7.y += a1.w*w.y; acc7.z += a1.w*w.z; acc7.w += a1.w*w.w;
        }
        __syncthreads();                       // done reading before next stage
    }
    float* op = Op + (bq << 3) * ldo + co + (cq << 2);
    *(float4*)(op)           = acc0;  *(float4*)(op + ldo)     = acc1;
    *(float4*)(op + 2 * ldo) = acc2;  *(float4*)(op + 3 * ldo) = acc3;
    *(float4*)(op + 4 * ldo) = acc4;  *(float4*)(op + 5 * ldo) = acc5;
    *(float4*)(op + 6 * ldo) = acc6;  *(float4*)(op + 7 * ldo) = acc7;
}

// 64b x 128c tile, np k-panels of 64. 512 thr: 4b x 4c each. Wt = 32KB.
__device__ __forceinline__ void gemm128(
    const float* AT, const float* Wp, int ldw, int wrows, int co, int np,
    bool wS, float* Op, int ldo, float* Wt, int tid)
{
    int cq = tid & 31, bq = tid >> 5;
    float4 acc0 = {0,0,0,0}, acc1 = {0,0,0,0}, acc2 = {0,0,0,0}, acc3 = {0,0,0,0};
    for (int pn = 0; pn < np; pn++) {
        if (!wS) {
            #pragma unroll
            for (int q = 0; q < 4; q++) {
                int s = (q << 9) + tid;        // float4 slot 0..2047
                int r = s >> 5, c4 = s & 31;
                int kr = (pn << 6) + r; if (kr >= wrows) kr = wrows - 1;
                gload_lds16(Wp + kr * ldw + co + (c4 << 2), Wt + (s << 2));
            }
        } else {
            #pragma unroll
            for (int q = 0; q < 16; q++) {
                int idx = (q << 9) + tid;      // 0..8191
                int r = idx >> 7, c = idx & 127;
                int kr = (pn << 6) + r; if (kr >= wrows) kr = wrows - 1;
                Wt[idx] = (c < OUT_DIM) ? Wp[kr * ldw + c] : 0.f;
            }
        }
        __syncthreads();
        const float* Ap2 = AT + (pn << 12) + (bq << 2);
        const float* Wcc = Wt + (cq << 2);
        #pragma unroll 8
        for (int k = 0; k < 64; k++) {
            float4 a = *(const float4*)(Ap2 + (k << 6));
            float4 w = *(const float4*)(Wcc + (k << 7));
            acc0.x += a.x*w.x; acc0.y += a.x*w.y; acc0.z += a.x*w.z; acc0.w += a.x*w.w;
            acc1.x += a.y*w.x; acc1.y += a.y*w.y; acc1.z += a.y*w.z; acc1.w += a.y*w.w;
            acc2.x += a.z*w.x; acc2.y += a.z*w.y; acc2.z += a.z*w.z; acc2.w += a.z*w.w;
            acc3.x += a.w*w.x; acc3.y += a.w*w.y; acc3.z += a.w*w.z; acc3.w += a.w*w.w;
        }
        __syncthreads();
    }
    float* op = Op + (bq << 2) * ldo + co + (cq << 2);
    *(float4*)(op)           = acc0;  *(float4*)(op + ldo)     = acc1;
    *(float4*)(op + 2 * ldo) = acc2;  *(float4*)(op + 3 * ldo) = acc3;
}

// ---------------------------------------------------------------------------
// K1: all tile GEMMs. grid 216 x 512. Unit map (k-chunks of 128, np panels):
//   [0,128)   hWh  8ch x 16ct (256c)  [128,160) gH 8ch x 4ct (256c)
//   [160,168) ghh  2ch x 4ct  (256c)  [168,200) xWx 32ct (128c, np=3)
//   [200,208) gx   8ct (128c, np=3)   [208,216) proj 8ch (128c, np=2, staged)
// Tail (t==NSEQ): proj only.
// ---------------------------------------------------------------------------
__global__ __launch_bounds__(512, 2) void k1_kernel(
    const float* __restrict__ Wx,      const float* __restrict__ Wh,
    const float* __restrict__ Wxh_hy,  const float* __restrict__ Whh_hy,
    const float* __restrict__ fc_proj_w, int t)
{
    __shared__ float pool[16384];       // 64 KB
    int u = blockIdx.x, tid = threadIdx.x;
    if (u < 128) {                              // h @ Wh (256-col)
        if (t < NSEQ) {
            int ch = u >> 4, ct = u & 15;
            gemm256(g_hT + ch * 128 * 64, Wh + ch * 128 * HD4,
                    HD4, 128, ct * 256, 2, g_hWh[ch], HD4, pool, tid);
        }
    } else if (u < 160) {                       // h-part hyper gates
        if (t < NSEQ) {
            int i = u - 128, ch = i >> 2, ct = i & 3;
            gemm256(g_hT + ch * 128 * 64, Wxh_hy + (133 + ch * 128) * HD,
                    HD, 128, ct * 256, 2, g_gH[ch], HD, pool, tid);
        }
    } else if (u < 168) {                       // hh @ Whh_hy
        if (t < NSEQ) {
            int i = u - 160, ch = i >> 2, ct = i & 3;
            gemm256(g_hhT + ch * 128 * 64, Whh_hy + ch * 128 * HD,
                    HD, 128, ct * 256, 2, g_ghh[ch], HD, pool, tid);
        }
    } else if (u < 200) {                       // x @ Wx (128-col)
        if (t < NSEQ) {
            int ct = u - 168;
            gemm128(g_xT + t * 192 * 64, Wx,
                    HD4, IN_DIM, ct * 128, 3, false, g_xWx, HD4, pool, tid);
        }
    } else if (u < 208) {                       // x-part hyper gates
        if (t < NSEQ) {
            int ct = u - 200;
            gemm128(g_xT + t * 192 * 64, Wxh_hy,
                    HD, IN_DIM, ct * 128, 3, false, g_gx, HD, pool, tid);
        }
    } else {                                    // proj of h_{t-1}
        if (t > 0) {
            int ch = u - 208;
            gemm128(g_hT + ch * 128 * 64, fc_proj_w + ch * 128 * OUT_DIM,
                    OUT_DIM, 128, 0, 2, true, g_proj[ch], 128, pool, tid);
        }
    }
}

// ---------------------------------------------------------------------------
// K2: blocks [0,64): gate-sum (11 arrays + b_hy) -> hh/ch -> z GEMV (1024 thr).
//     blocks [64,128): proj epilogue + MDN for t-1.
// ---------------------------------------------------------------------------
__global__ __launch_bounds__(1024) void k2_kernel(
    const float* __restrict__ b_hy,
    const float* __restrict__ Wzx, const float* __restrict__ bzx,
    const float* __restrict__ Wzh, const float* __restrict__ bzh,
    const float* __restrict__ Wzb,
    const float* __restrict__ fc_proj_b, float* __restrict__ out, int t)
{
    __shared__ float gsum[1024];
    __shared__ float hhB[256];
    int blk = blockIdx.x, tid = threadIdx.x;
    if (blk < 64) {
        if (t >= NSEQ) return;
        int b = blk, base = b * HD;
        {
            int j = tid;
            float a = b_hy[j];
            #pragma unroll
            for (int c = 0; c < 8; c++) a += g_gH[c][base + j];
            a += g_ghh[0][base + j] + g_ghh[1][base + j] + g_gx[base + j];
            gsum[j] = a;
        }
        __syncthreads();
        if (tid < 256) {
            float gi = gsum[tid],       gf = gsum[256 + tid];
            float gg = gsum[512 + tid], go = gsum[768 + tid];
            float ch = g_ch[b * HY + tid];
            ch = sigf(gf) * ch + sigf(gi) * tanhf(gg);
            float hh = sigf(go) * tanhf(ch);
            g_ch[b * HY + tid] = ch;
            g_hhT[tid * 64 + b] = hh;
            hhB[tid] = hh;
        }
        __syncthreads();
        if (tid < 768) {
            int ten = tid >> 8, oo = tid & 255;
            const float* Wz = (ten == 0) ? Wzx : (ten == 1) ? Wzh : Wzb;
            float acc = (ten == 0) ? bzx[oo] : (ten == 1) ? bzh[oo] : 0.f;
            #pragma unroll 8
            for (int k = 0; k < HY; k++) acc += hhB[k] * Wz[(k << 8) + oo];
            g_z[b * 768 + tid] = acc;
        }
    } else {
        if (t == 0) return;
        int b = blk - 64, tp = t - 1, base7 = b << 7;
        int c = tid;
        if (c < 120) {
            float v = fc_proj_b[c];
            #pragma unroll
            for (int q = 0; q < 8; q++) v += g_proj[q][base7 + c];
            int m = c / 6, r = c - m * 6;
            int oidx = tp * (MM * BB) + m * BB + b;
            if      (r == 0) out[oidx]          = 1.0f;   // size-1 softmax
            else if (r == 1) out[163840 + oidx] = v;
            else if (r == 2) out[327680 + oidx] = v;
            else if (r == 3) out[491520 + oidx] = expf(v);
            else if (r == 4) out[655360 + oidx] = expf(v);
            else             out[819200 + oidx] = tanhf(v);
        } else if (c == 120) {                   // pen-state softmax
            float p0 = fc_proj_b[120], p1 = fc_proj_b[121], p2 = fc_proj_b[122];
            #pragma unroll
            for (int q = 0; q < 8; q++) {
                p0 += g_proj[q][base7 + 120];
                p1 += g_proj[q][base7 + 121];
                p2 += g_proj[q][base7 + 122];
            }
            float mx = fmaxf(p0, fmaxf(p1, p2));
            float e0 = expf(p0 - mx), e1 = expf(p1 - mx), e2 = expf(p2 - mx);
            float s = e0 + e1 + e2;
            int ob = 983040 + tp * (BB * 3) + b * 3;
            out[ob + 0] = e0 / s; out[ob + 1] = e1 / s; out[ob + 2] = e2 / s;
        }
    }
}

// ---------------------------------------------------------------------------
// K3: einsum + combine 8 partials + main LSTM update. grid 256 x 512.
// ---------------------------------------------------------------------------
__global__ __launch_bounds__(512) void k3_kernel(
    const float* __restrict__ Dx, const float* __restrict__ Dh,
    const float* __restrict__ Db, const float* __restrict__ b0w)
{
    __shared__ float zC[6144];
    __shared__ float preC[1024];
    int blk = blockIdx.x, tid = threadIdx.x;
    int bg = blk >> 5, sl = blk & 31;
    int hi0 = sl << 5;
    {
        const float4* src = (const float4*)(g_z + bg * 8 * 768);
        float4* dst = (float4*)zC;
        for (int i = tid; i < 1536; i += 512) dst[i] = src[i];
    }
    __syncthreads();
    int hi_l = tid & 31, gq = (tid >> 5) & 3, b4 = tid >> 7;
    int hi = hi0 + hi_l;
    const float* dxp = Dx + gq * 64 * HD + hi;
    const float* dhp = Dh + gq * 64 * HD + hi;
    const float* dbp = Db + gq * 64 * HD + hi;
    const float* z0 = zC + b4 * 768;
    const float* z1 = zC + (b4 + 4) * 768;
    int zo = gq << 6;
    float ax0 = 0.f, ah0 = 0.f, ab0 = 0.f, ax1 = 0.f, ah1 = 0.f, ab1 = 0.f;
    #pragma unroll 4
    for (int f = 0; f < FF; f++) {
        float dx = dxp[f * HD], dh = dhp[f * HD], db = dbp[f * HD];
        ax0 += z0[zo + f] * dx; ah0 += z0[256 + zo + f] * dh;
        ab0 += z0[512 + zo + f] * db;
        ax1 += z1[zo + f] * dx; ah1 += z1[256 + zo + f] * dh;
        ab1 += z1[512 + zo + f] * db;
    }
    int idx = (gq << 10) + hi;
    int b0i = (bg << 3) + b4, b1i = b0i + 4;
    float hw0 = 0.f, hw1 = 0.f;
    #pragma unroll
    for (int q = 0; q < 8; q++) {
        hw0 += g_hWh[q][b0i * HD4 + idx];
        hw1 += g_hWh[q][b1i * HD4 + idx];
    }
    float xw0 = g_xWx[b0i * HD4 + idx], xw1 = g_xWx[b1i * HD4 + idx];
    float bw = b0w[idx];
    float pre0 = ax0 * xw0 + ah0 * hw0 + ab0 + bw;
    float pre1 = ax1 * xw1 + ah1 * hw1 + ab1 + bw;
    preC[((b4 << 2) + gq) * 32 + hi_l]       = pre0;
    preC[(((b4 + 4) << 2) + gq) * 32 + hi_l] = pre1;
    __syncthreads();
    if (tid < 256) {
        int bi = tid >> 5, hl = tid & 31;
        int b = (bg << 3) + bi, ha = b * HD + hi0 + hl;
        float pi = preC[((bi << 2) + 0) * 32 + hl];
        float pf = preC[((bi << 2) + 1) * 32 + hl];
        float pg = preC[((bi << 2) + 2) * 32 + hl];
        float po = preC[((bi << 2) + 3) * 32 + hl];
        float cv = g_c[ha];
        float nc = sigf(pf) * cv + sigf(pi) * tanhf(pg);
        float nh = sigf(po) * tanhf(nc);
        g_c[ha] = nc;
        g_hT[(hi0 + hl) * 64 + b] = nh;
    }
}

// ---------------------------------------------------------------------------
extern "C" void kernel_launch(void* const* d_in, const int* in_sizes, int n_in,
                              void* d_out, int out_size, void* d_ws, size_t ws_size,
                              hipStream_t stream)
{
    const float* z         = (const float*)d_in[0];
    const float* strokes   = (const float*)d_in[1];
    const float* fc_in_w   = (const float*)d_in[2];
    const float* fc_in_b   = (const float*)d_in[3];
    const float* fc_proj_w = (const float*)d_in[4];
    const float* fc_proj_b = (const float*)d_in[5];
    const float* Wx        = (const float*)d_in[6];
    const float* Wh        = (const float*)d_in[7];
    const float* b0w       = (const float*)d_in[8];
    const float* Wxh_hy    = (const float*)d_in[9];
    const float* Whh_hy    = (const float*)d_in[10];
    const float* b_hy      = (const float*)d_in[11];
    const float* Wzx       = (const float*)d_in[12];
    const float* bzx       = (const float*)d_in[13];
    const float* Wzh       = (const float*)d_in[14];
    const float* bzh       = (const float*)d_in[15];
    const float* Wzb       = (const float*)d_in[16];
    const float* Dx        = (const float*)d_in[17];
    const float* Dh        = (const float*)d_in[18];
    const float* Db        = (const float*)d_in[19];
    (void)d_ws; (void)ws_size; (void)in_sizes; (void)n_in; (void)out_size;
    float* out = (float*)d_out;

    init_kernel<<<64, 256, 0, stream>>>(z, fc_in_w, fc_in_b);
    xt_kernel<<<128, 256, 0, stream>>>(strokes);
    for (int t = 0; t < NSEQ; t++) {
        k1_kernel<<<216, 512, 0, stream>>>(Wx, Wh, Wxh_hy, Whh_hy, fc_proj_w, t);
        k2_kernel<<<128, 1024, 0, stream>>>(b_hy, Wzx, bzx, Wzh, bzh, Wzb,
                                            fc_proj_b, out, t);
        k3_kernel<<<256, 512, 0, stream>>>(Dx, Dh, Db, b0w);
    }
    // tail: proj + MDN for t = 127
    k1_kernel<<<216, 512, 0, stream>>>(Wx, Wh, Wxh_hy, Whh_hy, fc_proj_w, NSEQ);
    k2_kernel<<<128, 1024, 0, stream>>>(b_hy, Wzx, bzx, Wzh, bzh, Wzb,
                                        fc_proj_b, out, NSEQ);
}